// Round 6
// baseline (451.545 us; speedup 1.0000x reference)
//
#include <hip/hip_runtime.h>
#include <cstdint>
#include <cstddef>

#define B_ 4
#define T_ 2048
#define D_ 1024
#define H_ 16

typedef __attribute__((ext_vector_type(8))) short short8;     // 8 bf16 (4 VGPRs) for MFMA A/B frags
typedef __attribute__((ext_vector_type(4))) float f32x4;      // MFMA C/D frag
typedef __attribute__((ext_vector_type(8))) unsigned short u16x8;

__device__ __forceinline__ unsigned short f2b16(float f) {
  union { float f; unsigned int u; } un; un.f = f;
  unsigned int r = un.u + 0x7fffu + ((un.u >> 16) & 1u);  // round-to-nearest-even
  return (unsigned short)(r >> 16);
}
__device__ __forceinline__ void async_cp16(const void* g, void* l) {
  __builtin_amdgcn_global_load_lds((const __attribute__((address_space(1))) void*)g,
                                   (__attribute__((address_space(3))) void*)l,
                                   16, 0, 0);
}

// ---------------- LayerNorm: fp32 in -> bf16 normalized out -------------
__global__ __launch_bounds__(256) void ln_kernel(const float* __restrict__ x,
                                                 const float* __restrict__ gamma,
                                                 const float* __restrict__ beta,
                                                 unsigned short* __restrict__ xn) {
  const int row = blockIdx.x;
  const int t = threadIdx.x;
  const float4 v = ((const float4*)(x + (size_t)row * D_))[t];
  float s  = v.x + v.y + v.z + v.w;
  float s2 = v.x*v.x + v.y*v.y + v.z*v.z + v.w*v.w;
  #pragma unroll
  for (int off = 32; off > 0; off >>= 1) {
    s  += __shfl_down(s, off);
    s2 += __shfl_down(s2, off);
  }
  __shared__ float sh[8];
  const int wv = t >> 6, lane = t & 63;
  if (lane == 0) { sh[wv] = s; sh[4 + wv] = s2; }
  __syncthreads();
  if (t == 0) {
    float ts  = sh[0] + sh[1] + sh[2] + sh[3];
    float ts2 = sh[4] + sh[5] + sh[6] + sh[7];
    float mu  = ts * (1.0f / D_);
    float var = ts2 * (1.0f / D_) - mu * mu;
    sh[0] = mu;
    sh[1] = rsqrtf(var + 1e-5f);
  }
  __syncthreads();
  const float mu = sh[0], rs = sh[1];
  const float4 g  = ((const float4*)gamma)[t];
  const float4 bb = ((const float4*)beta)[t];
  ushort4 o;
  o.x = f2b16((v.x - mu) * rs * g.x + bb.x);
  o.y = f2b16((v.y - mu) * rs * g.y + bb.y);
  o.z = f2b16((v.z - mu) * rs * g.z + bb.z);
  o.w = f2b16((v.w - mu) * rs * g.w + bb.w);
  ((ushort4*)(xn + (size_t)row * D_))[t] = o;
}

// ---------- transpose + cast: w[K][N] fp32 -> wT[N][K] bf16 -------------
__global__ __launch_bounds__(256) void transpose_cast(const float* __restrict__ w,
                                                      unsigned short* __restrict__ wT,
                                                      int K, int N) {
  __shared__ float tile[32][33];
  const int n0 = blockIdx.x * 32;
  const int k0 = blockIdx.y * 32;
  const int tx = threadIdx.x, ty = threadIdx.y;
  #pragma unroll
  for (int i = 0; i < 32; i += 8)
    tile[ty + i][tx] = w[(size_t)(k0 + ty + i) * N + n0 + tx];
  __syncthreads();
  #pragma unroll
  for (int i = 0; i < 32; i += 8)
    wT[(size_t)(n0 + ty + i) * K + k0 + tx] = f2b16(tile[tx][ty + i]);
}

// ---- transpose V: vB[bh][t][dv] -> vtB[bh][dv][t'] (c' permuted) -------
// c'(t) within each 64-block: 4*(t&15) + 2*bit5(t) + bit4(t) — matches the
// attention P-tile column layout so PV is a plain dot over c'.
__global__ __launch_bounds__(256) void transpose_v(const unsigned short* __restrict__ vB,
                                                   unsigned short* __restrict__ vtB) {
  __shared__ unsigned short tile[64 * 66];
  const int tid = threadIdx.x;
  const int bh = blockIdx.x;
  const int t0 = blockIdx.y * 64;
  const int lr = tid >> 2, lc = (tid & 3) * 16;
  const unsigned short* src = vB + ((size_t)bh * T_ + t0) * 64;
  *(u16x8*)&tile[lr * 66 + lc]     = *(const u16x8*)(src + (size_t)lr * 64 + lc);
  *(u16x8*)&tile[lr * 66 + lc + 8] = *(const u16x8*)(src + (size_t)lr * 64 + lc + 8);
  __syncthreads();
  const int dv = tid >> 2, cb = (tid & 3) * 16;
  unsigned short outv[16];
  #pragma unroll
  for (int j = 0; j < 16; ++j) {
    const int c = cb + j;
    const int t = ((c >> 1) & 1) * 32 + (c & 1) * 16 + (c >> 2);
    outv[j] = tile[t * 66 + dv];
  }
  unsigned short* dst = vtB + ((size_t)bh * 64 + dv) * T_ + t0 + cb;
  *(u16x8*)dst       = *(const u16x8*)&outv[0];
  *(u16x8*)(dst + 8) = *(const u16x8*)&outv[8];
}

// ------------- MFMA GEMM: C = A(bf16) @ Bt(bf16)^T + bias --------------
// m97-verified structure: 128x128 tile, BK=32, global_load_lds width=16.
// MODE 0 (QKV): splits output into qB (scaled by 0.125*log2e), kB, vB
//               (all coalesced [bh][t][64] stores).
// MODE 1: out fp32 = acc + bias + residual.
template <int MODE>
__global__ __launch_bounds__(256) void gemm_bt(const unsigned short* __restrict__ A,
                                               const unsigned short* __restrict__ Bt,
                                               const float* __restrict__ bias,
                                               const float* __restrict__ resid,
                                               unsigned short* __restrict__ qB,
                                               unsigned short* __restrict__ kB,
                                               unsigned short* __restrict__ vB,
                                               float* __restrict__ outF,
                                               int M, int N, int K) {
  __shared__ unsigned short As[128 * 32];
  __shared__ unsigned short Bs[128 * 32];
  const int tid  = threadIdx.x;
  const int lane = tid & 63;
  const int wv   = tid >> 6;
  const int wm   = (wv & 1) * 64;
  const int wn   = (wv >> 1) * 64;
  const int tileM = blockIdx.x * 128;
  const int tileN = blockIdx.y * 128;
  const int l15 = lane & 15, quad = lane >> 4;
  const int sRow = tid >> 2;
  const int sCol = (tid & 3) * 8;

  f32x4 acc[4][4] = {};

  const unsigned short* aG0 = A  + (size_t)(tileM + sRow) * K + sCol;
  const unsigned short* aG1 = A  + (size_t)(tileM + 64 + sRow) * K + sCol;
  const unsigned short* bG0 = Bt + (size_t)(tileN + sRow) * K + sCol;
  const unsigned short* bG1 = Bt + (size_t)(tileN + 64 + sRow) * K + sCol;
  unsigned short* lA0 = &As[tid * 8];
  unsigned short* lA1 = &As[2048 + tid * 8];
  unsigned short* lB0 = &Bs[tid * 8];
  unsigned short* lB1 = &Bs[2048 + tid * 8];

  for (int k0 = 0; k0 < K; k0 += 32) {
    async_cp16(aG0 + k0, lA0);
    async_cp16(aG1 + k0, lA1);
    async_cp16(bG0 + k0, lB0);
    async_cp16(bG1 + k0, lB1);
    __syncthreads();

    short8 a[4], b[4];
    #pragma unroll
    for (int i = 0; i < 4; ++i) {
      a[i] = *(const short8*)&As[(wm + i * 16 + l15) * 32 + quad * 8];
      b[i] = *(const short8*)&Bs[(wn + i * 16 + l15) * 32 + quad * 8];
    }
    #pragma unroll
    for (int mi = 0; mi < 4; ++mi)
      #pragma unroll
      for (int ni = 0; ni < 4; ++ni)
        acc[mi][ni] = __builtin_amdgcn_mfma_f32_16x16x32_bf16(a[mi], b[ni], acc[mi][ni], 0, 0, 0);
    __syncthreads();
  }

  // epilogue: C/D layout col=lane&15, row=quad*4+r (m89/m91-verified)
  #pragma unroll
  for (int ni = 0; ni < 4; ++ni) {
    const int col = tileN + wn + ni * 16 + l15;
    const float bv = bias[col];
    #pragma unroll
    for (int mi = 0; mi < 4; ++mi) {
      #pragma unroll
      for (int r = 0; r < 4; ++r) {
        const int row = tileM + wm + mi * 16 + quad * 4 + r;
        const float v = acc[mi][ni][r] + bv;
        if (MODE == 1) {
          const size_t idx = (size_t)row * N + col;
          outF[idx] = v + resid[idx];
        } else {
          const int b = row >> 11, t = row & 2047;
          if (col < 1024) {          // Q, softmax scale folded in
            const int hh = col >> 6, d = col & 63;
            qB[((size_t)(b * 16 + hh) * T_ + t) * 64 + d] = f2b16(v * 0.180336880f);
          } else if (col < 2048) {   // K
            const int j = col - 1024, hh = j >> 6, d = j & 63;
            kB[((size_t)(b * 16 + hh) * T_ + t) * 64 + d] = f2b16(v);
          } else {                   // V (plain; transpose_v permutes later)
            const int j = col - 2048, hh = j >> 6, d = j & 63;
            vB[((size_t)(b * 16 + hh) * T_ + t) * 64 + d] = f2b16(v);
          }
        }
      }
    }
  }
}

// ---------------- MFMA flash attention v5 ------------------------------
// 4 waves x 32 q-rows, grid 1024 (4 blocks/CU). ZERO barriers in the body:
//  - K and V B-frags both load directly from global (kB row-major,
//    vtB transposed+permuted). 4 waves issue identical addresses ->
//    L1/L2 broadcast; tiles are XCD-local (bid&63 = bh, 64%8==0).
//  - P is the only LDS use: per-wave, DOUBLE-BUFFERED (kt&1) tile,
//    stride 72 (odd 16B chunk -> conflict-free b128 reads). Double
//    buffering breaks the write-after-read chain so iteration kt+1's
//    QK/exp2 pipelines with kt's PV. Waves never synchronize -> they
//    drift out of phase and co-schedule MFMA vs VALU vs LDS (m114).
// No-max softmax: P = exp2(S) (scale*log2e folded into Q upstream);
// denominator l accumulated by a constant all-ones B-frag MFMA.
__global__ __launch_bounds__(256, 4) void attn_mfma(const unsigned short* __restrict__ qB,
                                                    const unsigned short* __restrict__ kB,
                                                    const unsigned short* __restrict__ vtB,
                                                    unsigned short* __restrict__ aout) {
  __shared__ unsigned short Pw[4][2][32 * 72];  // per-wave double-buffered P

  const int tid = threadIdx.x;
  const int bid = blockIdx.x;
  const int bh = bid & 63;            // all 16 q-blocks of a bh on one XCD
  const int qb = bid >> 6;
  const int b = bh >> 4, h = bh & 15;
  const int wv = tid >> 6, lane = tid & 63;
  const int l15 = lane & 15, quad = lane >> 4;

  const unsigned short* qP = qB  + (size_t)bh * T_ * 64;
  const unsigned short* kP = kB  + (size_t)bh * T_ * 64;
  const unsigned short* vP = vtB + (size_t)bh * 64 * T_;
  const int q0 = qb * 128 + wv * 32;

  // resident Q fragments: A[m=l15][k=quad*8+j]
  short8 qf[2][2];
  #pragma unroll
  for (int mi = 0; mi < 2; ++mi)
    #pragma unroll
    for (int ks = 0; ks < 2; ++ks)
      qf[mi][ks] = *(const short8*)(qP + ((size_t)(q0 + mi * 16 + l15)) * 64 + ks * 32 + quad * 8);

  const short8 onesf = {0x3F80, 0x3F80, 0x3F80, 0x3F80, 0x3F80, 0x3F80, 0x3F80, 0x3F80};
  f32x4 accO[2][5] = {};

  for (int kt = 0; kt < 32; ++kt) {
    const unsigned short* kTile = kP + (size_t)kt * 64 * 64;
    const unsigned short* vTile = vP + kt * 64;

    // S = Q @ K^T ; kb B-frags straight from global (L1-served broadcast)
    f32x4 accS[2][4] = {};
    #pragma unroll
    for (int ks = 0; ks < 2; ++ks) {
      #pragma unroll
      for (int c = 0; c < 4; ++c) {
        const short8 kb = *(const short8*)(kTile + (size_t)(c * 16 + l15) * 64 + ks * 32 + quad * 8);
        accS[0][c] = __builtin_amdgcn_mfma_f32_16x16x32_bf16(qf[0][ks], kb, accS[0][c], 0, 0, 0);
        accS[1][c] = __builtin_amdgcn_mfma_f32_16x16x32_bf16(qf[1][ks], kb, accS[1][c], 0, 0, 0);
      }
    }

    // P = exp2(S) -> bf16 trunc, packed b64 write at c' = 4*l15 + c
    unsigned short* P = Pw[wv][kt & 1];
    #pragma unroll
    for (int mi = 0; mi < 2; ++mi) {
      #pragma unroll
      for (int r = 0; r < 4; ++r) {
        ushort4 pv;
        union { float f; unsigned int u; } e;
        e.f = __builtin_amdgcn_exp2f(accS[mi][0][r]); pv.x = (unsigned short)(e.u >> 16);
        e.f = __builtin_amdgcn_exp2f(accS[mi][1][r]); pv.y = (unsigned short)(e.u >> 16);
        e.f = __builtin_amdgcn_exp2f(accS[mi][2][r]); pv.z = (unsigned short)(e.u >> 16);
        e.f = __builtin_amdgcn_exp2f(accS[mi][3][r]); pv.w = (unsigned short)(e.u >> 16);
        *(ushort4*)&P[(mi * 16 + quad * 4 + r) * 72 + 4 * l15] = pv;
      }
    }

    // O += P @ V' : V B-frags direct from global; nj=4 = ones (l sum)
    #pragma unroll
    for (int ks = 0; ks < 2; ++ks) {
      short8 vb[4], pa[2];
      #pragma unroll
      for (int nj = 0; nj < 4; ++nj)
        vb[nj] = *(const short8*)(vTile + (size_t)(nj * 16 + l15) * T_ + ks * 32 + quad * 8);
      #pragma unroll
      for (int mi = 0; mi < 2; ++mi)
        pa[mi] = *(const short8*)&P[(mi * 16 + l15) * 72 + ks * 32 + quad * 8];
      #pragma unroll
      for (int mi = 0; mi < 2; ++mi) {
        #pragma unroll
        for (int nj = 0; nj < 4; ++nj)
          accO[mi][nj] = __builtin_amdgcn_mfma_f32_16x16x32_bf16(pa[mi], vb[nj], accO[mi][nj], 0, 0, 0);
        accO[mi][4] = __builtin_amdgcn_mfma_f32_16x16x32_bf16(pa[mi], onesf, accO[mi][4], 0, 0, 0);
      }
    }
  }

  // normalize by l (accO[mi][4][r], replicated across cols) and store bf16
  #pragma unroll
  for (int mi = 0; mi < 2; ++mi) {
    #pragma unroll
    for (int r = 0; r < 4; ++r) {
      const float inv = 1.0f / accO[mi][4][r];
      const int row = q0 + mi * 16 + quad * 4 + r;
      unsigned short* op = aout + (size_t)(b * T_ + row) * D_ + h * 64 + l15;
      #pragma unroll
      for (int nj = 0; nj < 4; ++nj)
        op[nj * 16] = f2b16(accO[mi][nj][r] * inv);
    }
  }
}

extern "C" void kernel_launch(void* const* d_in, const int* in_sizes, int n_in,
                              void* d_out, int out_size, void* d_ws, size_t ws_size,
                              hipStream_t stream) {
  const float* x      = (const float*)d_in[0];
  const float* w_qkv  = (const float*)d_in[1];
  const float* b_qkv  = (const float*)d_in[2];
  const float* w_proj = (const float*)d_in[3];
  const float* b_proj = (const float*)d_in[4];
  const float* ln_g   = (const float*)d_in[5];
  const float* ln_b   = (const float*)d_in[6];
  float* out = (float*)d_out;

  char* ws = (char*)d_ws;
  unsigned short* xn   = (unsigned short*)(ws);                       // 16 MB (reused as aout)
  unsigned short* wTq  = (unsigned short*)(ws + (size_t)(16 << 20));  //  6 MB
  unsigned short* wTp  = (unsigned short*)(ws + (size_t)(22 << 20));  //  2 MB
  unsigned short* qBuf = (unsigned short*)(ws + (size_t)(24 << 20));  // 16 MB
  unsigned short* kBuf = (unsigned short*)(ws + (size_t)(40 << 20));  // 16 MB
  unsigned short* vBuf = (unsigned short*)(ws + (size_t)(56 << 20));  // 16 MB
  unsigned short* vtB  = (unsigned short*)(ws + (size_t)(72 << 20));  // 16 MB
  unsigned short* aout = xn;   // xn is dead after gemm<0>; attn reuses it

  // 1. LayerNorm -> bf16
  ln_kernel<<<8192, 256, 0, stream>>>(x, ln_g, ln_b, xn);
  // 2. weights -> transposed bf16 (Bt layout for gemm_bt)
  transpose_cast<<<dim3(96, 32), dim3(32, 8), 0, stream>>>(w_qkv, wTq, 1024, 3072);
  transpose_cast<<<dim3(32, 32), dim3(32, 8), 0, stream>>>(w_proj, wTp, 1024, 1024);
  // 3. QKV projection -> qB (scaled), kB, vB (all coalesced)
  gemm_bt<0><<<dim3(64, 24), 256, 0, stream>>>(xn, wTq, b_qkv, nullptr,
                                               qBuf, kBuf, vBuf, nullptr, 8192, 3072, 1024);
  // 3b. V -> V^T with c' permutation
  transpose_v<<<dim3(64, 32), 256, 0, stream>>>(vBuf, vtB);
  // 4. MFMA flash attention (barrier-free body)
  attn_mfma<<<1024, 256, 0, stream>>>(qBuf, kBuf, vtB, aout);
  // 5. output projection + bias + residual, fp32 out
  gemm_bt<1><<<dim3(64, 8), 256, 0, stream>>>(aout, wTp, b_proj, x,
                                              nullptr, nullptr, nullptr, out, 8192, 1024, 1024);
}

// Round 7
// 304.273 us; speedup vs baseline: 1.4840x; 1.4840x over previous
//
#include <hip/hip_runtime.h>
#include <cstdint>
#include <cstddef>

#define B_ 4
#define T_ 2048
#define D_ 1024
#define H_ 16

typedef __attribute__((ext_vector_type(8))) short short8;     // 8 bf16 (4 VGPRs) for MFMA A/B frags
typedef __attribute__((ext_vector_type(4))) float f32x4;      // MFMA C/D frag
typedef __attribute__((ext_vector_type(8))) unsigned short u16x8;

__device__ __forceinline__ unsigned short f2b16(float f) {
  union { float f; unsigned int u; } un; un.f = f;
  unsigned int r = un.u + 0x7fffu + ((un.u >> 16) & 1u);  // round-to-nearest-even
  return (unsigned short)(r >> 16);
}
__device__ __forceinline__ void async_cp16(const void* g, void* l) {
  __builtin_amdgcn_global_load_lds((const __attribute__((address_space(1))) void*)g,
                                   (__attribute__((address_space(3))) void*)l,
                                   16, 0, 0);
}

// ---------------- LayerNorm: fp32 in -> bf16 normalized out -------------
__global__ __launch_bounds__(256) void ln_kernel(const float* __restrict__ x,
                                                 const float* __restrict__ gamma,
                                                 const float* __restrict__ beta,
                                                 unsigned short* __restrict__ xn) {
  const int row = blockIdx.x;
  const int t = threadIdx.x;
  const float4 v = ((const float4*)(x + (size_t)row * D_))[t];
  float s  = v.x + v.y + v.z + v.w;
  float s2 = v.x*v.x + v.y*v.y + v.z*v.z + v.w*v.w;
  #pragma unroll
  for (int off = 32; off > 0; off >>= 1) {
    s  += __shfl_down(s, off);
    s2 += __shfl_down(s2, off);
  }
  __shared__ float sh[8];
  const int wv = t >> 6, lane = t & 63;
  if (lane == 0) { sh[wv] = s; sh[4 + wv] = s2; }
  __syncthreads();
  if (t == 0) {
    float ts  = sh[0] + sh[1] + sh[2] + sh[3];
    float ts2 = sh[4] + sh[5] + sh[6] + sh[7];
    float mu  = ts * (1.0f / D_);
    float var = ts2 * (1.0f / D_) - mu * mu;
    sh[0] = mu;
    sh[1] = rsqrtf(var + 1e-5f);
  }
  __syncthreads();
  const float mu = sh[0], rs = sh[1];
  const float4 g  = ((const float4*)gamma)[t];
  const float4 bb = ((const float4*)beta)[t];
  ushort4 o;
  o.x = f2b16((v.x - mu) * rs * g.x + bb.x);
  o.y = f2b16((v.y - mu) * rs * g.y + bb.y);
  o.z = f2b16((v.z - mu) * rs * g.z + bb.z);
  o.w = f2b16((v.w - mu) * rs * g.w + bb.w);
  ((ushort4*)(xn + (size_t)row * D_))[t] = o;
}

// ---------- transpose + cast: w[K][N] fp32 -> wT[N][K] bf16 -------------
__global__ __launch_bounds__(256) void transpose_cast(const float* __restrict__ w,
                                                      unsigned short* __restrict__ wT,
                                                      int K, int N) {
  __shared__ float tile[32][33];
  const int n0 = blockIdx.x * 32;
  const int k0 = blockIdx.y * 32;
  const int tx = threadIdx.x, ty = threadIdx.y;
  #pragma unroll
  for (int i = 0; i < 32; i += 8)
    tile[ty + i][tx] = w[(size_t)(k0 + ty + i) * N + n0 + tx];
  __syncthreads();
  #pragma unroll
  for (int i = 0; i < 32; i += 8)
    wT[(size_t)(n0 + ty + i) * K + k0 + tx] = f2b16(tile[tx][ty + i]);
}

// ---- transpose V: vB[bh][t][dv] -> vtB[bh][dv][t'] (c' permuted) -------
// c'(t) within each 64-block: 4*(t&15) + 2*bit5(t) + bit4(t) — matches the
// attention P-tile column layout so PV is a plain dot over c'.
__global__ __launch_bounds__(256) void transpose_v(const unsigned short* __restrict__ vB,
                                                   unsigned short* __restrict__ vtB) {
  __shared__ unsigned short tile[64 * 66];
  const int tid = threadIdx.x;
  const int bh = blockIdx.x;
  const int t0 = blockIdx.y * 64;
  const int lr = tid >> 2, lc = (tid & 3) * 16;
  const unsigned short* src = vB + ((size_t)bh * T_ + t0) * 64;
  *(u16x8*)&tile[lr * 66 + lc]     = *(const u16x8*)(src + (size_t)lr * 64 + lc);
  *(u16x8*)&tile[lr * 66 + lc + 8] = *(const u16x8*)(src + (size_t)lr * 64 + lc + 8);
  __syncthreads();
  const int dv = tid >> 2, cb = (tid & 3) * 16;
  unsigned short outv[16];
  #pragma unroll
  for (int j = 0; j < 16; ++j) {
    const int c = cb + j;
    const int t = ((c >> 1) & 1) * 32 + (c & 1) * 16 + (c >> 2);
    outv[j] = tile[t * 66 + dv];
  }
  unsigned short* dst = vtB + ((size_t)bh * 64 + dv) * T_ + t0 + cb;
  *(u16x8*)dst       = *(const u16x8*)&outv[0];
  *(u16x8*)(dst + 8) = *(const u16x8*)&outv[8];
}

// ------------- MFMA GEMM: C = A(bf16) @ Bt(bf16)^T + bias --------------
// m97-verified structure: 128x128 tile, BK=32, global_load_lds width=16.
// MODE 0 (QKV): splits output into qB (scaled by 0.125*log2e), kB, vB.
//   Epilogue stages each wave's 64x64 tile through per-wave LDS scratch
//   (wave-local, no barrier) -> 8 fully-coalesced 1KB b128 row stores
//   (replaces the old 2-byte scatter stores).
// MODE 1: out fp32 = acc + bias + residual (old epilogue).
template <int MODE>
__global__ __launch_bounds__(256) void gemm_bt(const unsigned short* __restrict__ A,
                                               const unsigned short* __restrict__ Bt,
                                               const float* __restrict__ bias,
                                               const float* __restrict__ resid,
                                               unsigned short* __restrict__ qB,
                                               unsigned short* __restrict__ kB,
                                               unsigned short* __restrict__ vB,
                                               float* __restrict__ outF,
                                               int M, int N, int K) {
  __shared__ unsigned short As[128 * 32];
  __shared__ unsigned short Bs[128 * 32];
  const int tid  = threadIdx.x;
  const int lane = tid & 63;
  const int wv   = tid >> 6;
  const int wm   = (wv & 1) * 64;
  const int wn   = (wv >> 1) * 64;
  const int tileM = blockIdx.x * 128;
  const int tileN = blockIdx.y * 128;
  const int l15 = lane & 15, quad = lane >> 4;
  const int sRow = tid >> 2;
  const int sCol = (tid & 3) * 8;

  f32x4 acc[4][4] = {};

  const unsigned short* aG0 = A  + (size_t)(tileM + sRow) * K + sCol;
  const unsigned short* aG1 = A  + (size_t)(tileM + 64 + sRow) * K + sCol;
  const unsigned short* bG0 = Bt + (size_t)(tileN + sRow) * K + sCol;
  const unsigned short* bG1 = Bt + (size_t)(tileN + 64 + sRow) * K + sCol;
  unsigned short* lA0 = &As[tid * 8];
  unsigned short* lA1 = &As[2048 + tid * 8];
  unsigned short* lB0 = &Bs[tid * 8];
  unsigned short* lB1 = &Bs[2048 + tid * 8];

  for (int k0 = 0; k0 < K; k0 += 32) {
    async_cp16(aG0 + k0, lA0);
    async_cp16(aG1 + k0, lA1);
    async_cp16(bG0 + k0, lB0);
    async_cp16(bG1 + k0, lB1);
    __syncthreads();

    short8 a[4], b[4];
    #pragma unroll
    for (int i = 0; i < 4; ++i) {
      a[i] = *(const short8*)&As[(wm + i * 16 + l15) * 32 + quad * 8];
      b[i] = *(const short8*)&Bs[(wn + i * 16 + l15) * 32 + quad * 8];
    }
    #pragma unroll
    for (int mi = 0; mi < 4; ++mi)
      #pragma unroll
      for (int ni = 0; ni < 4; ++ni)
        acc[mi][ni] = __builtin_amdgcn_mfma_f32_16x16x32_bf16(a[mi], b[ni], acc[mi][ni], 0, 0, 0);
    __syncthreads();
  }

  // epilogue: C/D layout col=lane&15, row=quad*4+r (m89/m91-verified)
  if constexpr (MODE == 1) {
    #pragma unroll
    for (int ni = 0; ni < 4; ++ni) {
      const int col = tileN + wn + ni * 16 + l15;
      const float bv = bias[col];
      #pragma unroll
      for (int mi = 0; mi < 4; ++mi) {
        #pragma unroll
        for (int r = 0; r < 4; ++r) {
          const int row = tileM + wm + mi * 16 + quad * 4 + r;
          const size_t idx = (size_t)row * N + col;
          outF[idx] = acc[mi][ni][r] + bv + resid[idx];
        }
      }
    }
  } else {
    // per-wave LDS transpose scratch -> coalesced b128 stores
    __shared__ unsigned short Es[4][64 * 72];
    unsigned short* E = Es[wv];
    const int colBase = tileN + wn;          // multiple of 64: one (sec,head) slice
    #pragma unroll
    for (int ni = 0; ni < 4; ++ni) {
      const int col = colBase + ni * 16 + l15;
      const float bv = bias[col];
      const float sc = (col < 1024) ? 0.180336880f : 1.0f;  // Q: fold 0.125*log2e
      #pragma unroll
      for (int mi = 0; mi < 4; ++mi)
        #pragma unroll
        for (int r = 0; r < 4; ++r)
          E[(mi * 16 + quad * 4 + r) * 72 + ni * 16 + l15] =
              f2b16((acc[mi][ni][r] + bv) * sc);
    }
    const int sec = colBase >> 10;           // 0=Q, 1=K, 2=V
    const int hh  = (colBase & 1023) >> 6;
    unsigned short* outSec = (sec == 0) ? qB : (sec == 1) ? kB : vB;
    #pragma unroll
    for (int it = 0; it < 8; ++it) {
      const int lrow = it * 8 + (lane >> 3);
      const int row = tileM + wm + lrow;
      const int b_ = row >> 11, t = row & 2047;
      const u16x8 val = *(const u16x8*)&E[lrow * 72 + (lane & 7) * 8];
      *(u16x8*)(outSec + ((size_t)(b_ * 16 + hh) * T_ + t) * 64 + (lane & 7) * 8) = val;
    }
  }
}

// ---------------- MFMA flash attention v7 ------------------------------
// 4 waves x 32 q-rows, grid 1024 (3 blocks/CU at 50 KB LDS). Both K and V
// staged via global_load_lds DMA into double-buffered XOR-chunk-swizzled
// tiles (chunk' = c ^ (row&7)): fully-coalesced wave DMA, zero staging
// VGPRs, conflict-free ds_read_b128 frags, ONE barrier per tile. (R6
// lesson: frag-shaped direct-global reads = 16 segments/instr -> TA-bound.)
// P: per-wave LDS tile stride 72 (odd chunk -> conflict-free), wave-local
// so no barrier involvement. No-max softmax: P = exp2(S) (scale*log2e
// folded into Q upstream); denominator l via constant all-ones B-frag MFMA.
__global__ __launch_bounds__(256, 3) void attn_mfma(const unsigned short* __restrict__ qB,
                                                    const unsigned short* __restrict__ kB,
                                                    const unsigned short* __restrict__ vtB,
                                                    unsigned short* __restrict__ aout) {
  __shared__ unsigned short Ks[2][64 * 64];   // swizzled K tiles [kv][hd]
  __shared__ unsigned short Vs[2][64 * 64];   // swizzled V^T tiles [dv][c']
  __shared__ unsigned short Pw[4][32 * 72];   // per-wave P [q][c'], stride 72

  const int tid = threadIdx.x;
  const int bid = blockIdx.x;
  const int bh = bid & 63;            // all 16 q-blocks of a bh on one XCD
  const int qb = bid >> 6;
  const int b = bh >> 4, h = bh & 15;
  const int wv = tid >> 6, lane = tid & 63;
  const int l15 = lane & 15, quad = lane >> 4;

  const unsigned short* qP = qB  + (size_t)bh * T_ * 64;
  const unsigned short* kP = kB  + (size_t)bh * T_ * 64;
  const unsigned short* vP = vtB + (size_t)bh * 64 * T_;
  const int q0 = qb * 128 + wv * 32;

  // resident Q fragments: A[m=l15][k=quad*8+j]
  short8 qf[2][2];
  #pragma unroll
  for (int mi = 0; mi < 2; ++mi)
    #pragma unroll
    for (int ks = 0; ks < 2; ++ks)
      qf[mi][ks] = *(const short8*)(qP + ((size_t)(q0 + mi * 16 + l15)) * 64 + ks * 32 + quad * 8);

  const short8 onesf = {0x3F80, 0x3F80, 0x3F80, 0x3F80, 0x3F80, 0x3F80, 0x3F80, 0x3F80};
  f32x4 accO[2][5] = {};

  // DMA mapping: wave stages rows w2*8..+8 (w2 = wv*2+{0,1}) of each tile.
  // Lane reads global chunk (row = w2*8 + lane>>3, c = (lane&7)^(row&7));
  // lands at LDS linear chunk w2*64 + lane -> LDS[row][c^(row&7)].
  const int lrow  = lane >> 3;
  const int lchnk = (lane & 7) ^ (lrow & 7);
  const size_t kOff0 = (size_t)((wv * 2 + 0) * 8 + lrow) * 64 + lchnk * 8;
  const size_t kOff1 = (size_t)((wv * 2 + 1) * 8 + lrow) * 64 + lchnk * 8;
  const size_t vOff0 = (size_t)((wv * 2 + 0) * 8 + lrow) * T_ + lchnk * 8;
  const size_t vOff1 = (size_t)((wv * 2 + 1) * 8 + lrow) * T_ + lchnk * 8;
  const int lOff0 = (wv * 2 + 0) * 512 + lane * 8;
  const int lOff1 = (wv * 2 + 1) * 512 + lane * 8;

  // stage tile 0
  async_cp16(kP + kOff0, &Ks[0][lOff0]);
  async_cp16(kP + kOff1, &Ks[0][lOff1]);
  async_cp16(vP + vOff0, &Vs[0][lOff0]);
  async_cp16(vP + vOff1, &Vs[0][lOff1]);
  __syncthreads();   // drains vmcnt(0): tile 0 visible

  for (int kt = 0; kt < 32; ++kt) {
    const int buf = kt & 1;
    if (kt + 1 < 32) {  // DMA next tile into the other buffer (early issue;
                        // safe: buf^1's readers finished before kt's start barrier)
      const unsigned short* kg = kP + (size_t)(kt + 1) * 64 * 64;
      const unsigned short* vg = vP + (kt + 1) * 64;
      async_cp16(kg + kOff0, &Ks[buf ^ 1][lOff0]);
      async_cp16(kg + kOff1, &Ks[buf ^ 1][lOff1]);
      async_cp16(vg + vOff0, &Vs[buf ^ 1][lOff0]);
      async_cp16(vg + vOff1, &Vs[buf ^ 1][lOff1]);
    }
    const unsigned short* K_ = Ks[buf];
    const unsigned short* V_ = Vs[buf];
    unsigned short* P = Pw[wv];

    // S = Q @ K^T ; kb frags from swizzled LDS (conflict-free b128)
    f32x4 accS[2][4] = {};
    #pragma unroll
    for (int ks = 0; ks < 2; ++ks) {
      #pragma unroll
      for (int c = 0; c < 4; ++c) {
        const short8 kb = *(const short8*)&K_[(c * 16 + l15) * 64 +
                                              (((ks << 2) | quad) ^ (l15 & 7)) * 8];
        accS[0][c] = __builtin_amdgcn_mfma_f32_16x16x32_bf16(qf[0][ks], kb, accS[0][c], 0, 0, 0);
        accS[1][c] = __builtin_amdgcn_mfma_f32_16x16x32_bf16(qf[1][ks], kb, accS[1][c], 0, 0, 0);
      }
    }

    // P = exp2(S) -> bf16 trunc, packed b64 write at c' = 4*l15 + c
    #pragma unroll
    for (int mi = 0; mi < 2; ++mi) {
      #pragma unroll
      for (int r = 0; r < 4; ++r) {
        ushort4 pv;
        union { float f; unsigned int u; } e;
        e.f = __builtin_amdgcn_exp2f(accS[mi][0][r]); pv.x = (unsigned short)(e.u >> 16);
        e.f = __builtin_amdgcn_exp2f(accS[mi][1][r]); pv.y = (unsigned short)(e.u >> 16);
        e.f = __builtin_amdgcn_exp2f(accS[mi][2][r]); pv.z = (unsigned short)(e.u >> 16);
        e.f = __builtin_amdgcn_exp2f(accS[mi][3][r]); pv.w = (unsigned short)(e.u >> 16);
        *(ushort4*)&P[(mi * 16 + quad * 4 + r) * 72 + 4 * l15] = pv;
      }
    }

    // O += P @ V' ; vb frags from swizzled LDS; nj=4 = ones (l sum)
    #pragma unroll
    for (int ks = 0; ks < 2; ++ks) {
      short8 vb[4], pa[2];
      #pragma unroll
      for (int nj = 0; nj < 4; ++nj)
        vb[nj] = *(const short8*)&V_[(nj * 16 + l15) * 64 +
                                     (((ks << 2) | quad) ^ (l15 & 7)) * 8];
      #pragma unroll
      for (int mi = 0; mi < 2; ++mi)
        pa[mi] = *(const short8*)&P[(mi * 16 + l15) * 72 + ks * 32 + quad * 8];
      #pragma unroll
      for (int mi = 0; mi < 2; ++mi) {
        #pragma unroll
        for (int nj = 0; nj < 4; ++nj)
          accO[mi][nj] = __builtin_amdgcn_mfma_f32_16x16x32_bf16(pa[mi], vb[nj], accO[mi][nj], 0, 0, 0);
        accO[mi][4] = __builtin_amdgcn_mfma_f32_16x16x32_bf16(pa[mi], onesf, accO[mi][4], 0, 0, 0);
      }
    }

    __syncthreads();  // single barrier: drains next-tile DMA + guards buffers
  }

  // normalize by l (accO[mi][4][r], replicated across cols) and store bf16
  #pragma unroll
  for (int mi = 0; mi < 2; ++mi) {
    #pragma unroll
    for (int r = 0; r < 4; ++r) {
      const float inv = 1.0f / accO[mi][4][r];
      const int row = q0 + mi * 16 + quad * 4 + r;
      unsigned short* op = aout + (size_t)(b * T_ + row) * D_ + h * 64 + l15;
      #pragma unroll
      for (int nj = 0; nj < 4; ++nj)
        op[nj * 16] = f2b16(accO[mi][nj][r] * inv);
    }
  }
}

extern "C" void kernel_launch(void* const* d_in, const int* in_sizes, int n_in,
                              void* d_out, int out_size, void* d_ws, size_t ws_size,
                              hipStream_t stream) {
  const float* x      = (const float*)d_in[0];
  const float* w_qkv  = (const float*)d_in[1];
  const float* b_qkv  = (const float*)d_in[2];
  const float* w_proj = (const float*)d_in[3];
  const float* b_proj = (const float*)d_in[4];
  const float* ln_g   = (const float*)d_in[5];
  const float* ln_b   = (const float*)d_in[6];
  float* out = (float*)d_out;

  char* ws = (char*)d_ws;
  unsigned short* xn   = (unsigned short*)(ws);                       // 16 MB (reused as aout)
  unsigned short* wTq  = (unsigned short*)(ws + (size_t)(16 << 20));  //  6 MB
  unsigned short* wTp  = (unsigned short*)(ws + (size_t)(22 << 20));  //  2 MB
  unsigned short* qBuf = (unsigned short*)(ws + (size_t)(24 << 20));  // 16 MB
  unsigned short* kBuf = (unsigned short*)(ws + (size_t)(40 << 20));  // 16 MB
  unsigned short* vBuf = (unsigned short*)(ws + (size_t)(56 << 20));  // 16 MB
  unsigned short* vtB  = (unsigned short*)(ws + (size_t)(72 << 20));  // 16 MB
  unsigned short* aout = xn;   // xn is dead after gemm<0>; attn reuses it

  // 1. LayerNorm -> bf16
  ln_kernel<<<8192, 256, 0, stream>>>(x, ln_g, ln_b, xn);
  // 2. weights -> transposed bf16 (Bt layout for gemm_bt)
  transpose_cast<<<dim3(96, 32), dim3(32, 8), 0, stream>>>(w_qkv, wTq, 1024, 3072);
  transpose_cast<<<dim3(32, 32), dim3(32, 8), 0, stream>>>(w_proj, wTp, 1024, 1024);
  // 3. QKV projection -> qB (scaled), kB, vB (coalesced b128 epilogue)
  gemm_bt<0><<<dim3(64, 24), 256, 0, stream>>>(xn, wTq, b_qkv, nullptr,
                                               qBuf, kBuf, vBuf, nullptr, 8192, 3072, 1024);
  // 3b. V -> V^T with c' permutation
  transpose_v<<<dim3(64, 32), 256, 0, stream>>>(vBuf, vtB);
  // 4. MFMA flash attention (K+V DMA-staged, 1 barrier/tile)
  attn_mfma<<<1024, 256, 0, stream>>>(qBuf, kBuf, vtB, aout);
  // 5. output projection + bias + residual, fp32 out
  gemm_bt<1><<<dim3(64, 8), 256, 0, stream>>>(aout, wTp, b_proj, x,
                                              nullptr, nullptr, nullptr, out, 8192, 1024, 1024);
}